// Round 22
// baseline (62.115 us; speedup 1.0000x reference)
//
#include <hip/hip_runtime.h>
#include <math.h>

#define NN 1024
#define B_C 64
#define L_C 160000
#define T_C 622
#define F_C 513
#define TT 16
#define NTILE ((T_C + TT - 1) / TT)   // 39
#define NBLK (B_C * NTILE)            // 2496 = 8 * 312
#define WIN_MIN_C (1024.0f / 20.0f)
#define WIN_MAX_C 1024.0f
#define TWO_PI 6.28318530717958647692f

typedef unsigned uv2 __attribute__((ext_vector_type(2)));
typedef float v2f __attribute__((ext_vector_type(2)));

__device__ __forceinline__ int brev6(int x) {
    return ((x & 1) << 5) | ((x & 2) << 3) | ((x & 4) << 1) |
           ((x & 8) >> 1) | ((x & 16) >> 3) | ((x & 32) >> 5);
}

// packed complex multiply: r = d * (cs.x + i*cs.y); d = {re, im}. 2 VOP3P ops.
__device__ __forceinline__ v2f cmul_pk(v2f d, v2f cs) {
    v2f t, r;
    asm("v_pk_mul_f32 %0, %1, %2 op_sel_hi:[1,0]"
        : "=v"(t) : "v"(d), "v"(cs));
    asm("v_pk_fma_f32 %0, %1, %2, %3 op_sel:[1,1,0] op_sel_hi:[0,1,1] neg_lo:[1,0,0]"
        : "=v"(r) : "v"(d), "v"(cs), "v"(t));
    return r;
}

// ---- lane-exchange helpers ----
__device__ __forceinline__ float lane_xor32(float v, int l) {
#if __has_builtin(__builtin_amdgcn_permlane32_swap)
    uv2 r = __builtin_amdgcn_permlane32_swap(__float_as_uint(v), __float_as_uint(v),
                                             false, false);
    return __uint_as_float((l & 32) ? r.x : r.y);
#else
    return __shfl_xor(v, 32, 64);
#endif
}
__device__ __forceinline__ float lane_xor8(float v) {   // row_ror:8 == xor8
    return __int_as_float(__builtin_amdgcn_update_dpp(
        __float_as_int(v), __float_as_int(v), 0x128, 0xF, 0xF, false));
}
__device__ __forceinline__ float lane_xor4(float v) {   // ds_swizzle xor4
    return __int_as_float(__builtin_amdgcn_ds_swizzle(__float_as_int(v), 0x101F));
}
__device__ __forceinline__ float lane_xor2(float v) {   // quad_perm [2,3,0,1]
    return __int_as_float(__builtin_amdgcn_update_dpp(
        __float_as_int(v), __float_as_int(v), 0x4E, 0xF, 0xF, false));
}
__device__ __forceinline__ float lane_xor1(float v) {   // quad_perm [1,0,3,2]
    return __int_as_float(__builtin_amdgcn_update_dpp(
        __float_as_int(v), __float_as_int(v), 0xB1, 0xF, 0xF, false));
}
__device__ __forceinline__ float lane_xor16(float v, int l) {
#if __has_builtin(__builtin_amdgcn_permlane16_swap)
    uv2 r = __builtin_amdgcn_permlane16_swap(__float_as_uint(v), __float_as_uint(v),
                                             false, false);
    return __uint_as_float((l & 16) ? r.x : r.y);
#else
    return __shfl_xor(v, 16, 64);
#endif
}
__device__ __forceinline__ float lane_xor31(float v) {  // ds_swizzle xor31
    return __int_as_float(__builtin_amdgcn_ds_swizzle(__float_as_int(v), 0x7C1F));
}
__device__ __forceinline__ float lane_xor63(float v, int l) {
    return lane_xor32(lane_xor31(v), l);   // 31 ^ 32 = 63, DS + VALU
}
__device__ __forceinline__ float fast_sqrtf(float x) {
#if __has_builtin(__builtin_amdgcn_sqrtf)
    return __builtin_amdgcn_sqrtf(x);
#else
    return sqrtf(x);
#endif
}

// --- Kernel: 8 waves/block, packed-fp32 FFT, inline taps, XCD-paired tiles ---
__global__ __launch_bounds__(512, 4) void fftw_kernel(
    const float* __restrict__ x,        // [B_C][L_C]
    const float* __restrict__ win_length,
    const float* __restrict__ strides,
    const float* __restrict__ win_pow,
    float* __restrict__ out)            // [B_C][F_C][T_C]
{
    // XCD-pairing remap (bijective on [0, NBLK)): adjacent tile pairs land
    // on the same XCD's L2 -> write cacheline merging + input read sharing.
    const int bid = blockIdx.x;
    const int xcd = bid & 7;
    const int slot = bid >> 3;
    const int q_ = slot & 1;
    const int chunk = slot >> 1;
    const int work = 2 * (xcd + 8 * chunk) + q_;
    const int tile = work % NTILE;
    const int b = work / NTILE;

    const int t0 = tile * TT;
    const int tid = threadIdx.x;
    const int w = tid >> 6;      // wave id 0..7 = frame pair
    const int l = tid & 63;      // lane

    const float wl = fminf(fmaxf(win_length[0], WIN_MIN_C), WIN_MAX_C);
    const float st = fminf(fmaxf(strides[0], 0.0f), WIN_MAX_C);
    const float wp = win_pow[0];
    const bool pow_one = (wp == 1.0f);

    // Hann window parameters (wave-uniform)
    const float hib = ceilf(((float)NN - 1.0f + wl) * 0.5f);
    const float lob = floorf(((float)NN - 1.0f - wl) * 0.5f);
    const float off = (wl - (float)NN + 1.0f) * 0.5f;
    const float inv_wl = 1.0f / wl;

    const float* xb = x + (size_t)b * L_C;

    __shared__ float mag[TT][F_C + 16];   // 529-float rows: stride%32=17, coprime

    const int bl = brev6(l);
    const int l2 = brev6((64 - bl) & 63);   // unpack partner lane for k1==0 reg

    constexpr int BR4[16]     = {0,8,4,12,2,10,6,14,1,9,5,13,3,11,7,15};
    constexpr int PARTNER[16] = {0,1,3,2,7,6,5,4,15,14,13,12,11,10,9,8};
    constexpr float C16[8] = {1.0f, 0.92387953251f, 0.70710678119f, 0.38268343236f,
                              0.0f, -0.38268343236f, -0.70710678119f, -0.92387953251f};
    constexpr float S16[8] = {0.0f, -0.38268343236f, -0.70710678119f, -0.92387953251f,
                              -1.0f, -0.92387953251f, -0.70710678119f, -0.38268343236f};

    const int jp = w;                   // pair index 0..7
    const int tA = t0 + 2 * jp;
    const int tB = tA + 1;
    const bool hasA = (tA < T_C);
    const bool hasB = (tB < T_C);
    const float frameA = (float)tA * st;
    const float fracA = frameA - floorf(frameA);
    const float frameB = (float)tB * st;
    const float fracB = frameB - floorf(frameB);
    const int idxA = hasA ? (int)floorf(frameA) : 0;
    const int idxB = hasB ? (int)floorf(frameB) : 0;

    v2f v[16];   // v[i].x = frame A (re), v[i].y = frame B (im)

    // ---- load + inline-tap taper; wave-uniform in-bounds fast path
    const bool okA = hasA && (idxA >= 0) && (idxA + NN <= L_C);
    const bool okB = hasB && (idxB >= 0) && (idxB + NN <= L_C);
    if (okA && okB && pow_one && fracA == fracB) {
        // shared window: one cos per element, one normalization
        float h[16];
        float sA = 0.0f;
#pragma unroll
        for (int r = 0; r < 16; ++r) {
            const int n = r * 64 + l;
            const float baseA = (float)n - fracA;
            float hA = 0.5f - 0.5f * __cosf(TWO_PI * (baseA + off) * inv_wl);
            hA = (baseA >= hib || baseA <= lob) ? 0.0f : hA;
            h[r] = hA;
            sA += hA;
        }
        if (idxB - idxA == 256) {
            // overlapped frames: B[n] = A[n + 256] -> reuse 12 of 16 loads
            float raw[20];
#pragma unroll
            for (int r = 0; r < 20; ++r) raw[r] = xb[idxA + r * 64 + l];
#pragma unroll
            for (int r = 0; r < 16; ++r) {
                v[r].x = raw[r] * h[r];
                v[r].y = raw[r + 4] * h[r];
            }
        } else {
#pragma unroll
            for (int r = 0; r < 16; ++r) {
                const int n = r * 64 + l;
                v[r].x = xb[idxA + n] * h[r];
                v[r].y = xb[idxB + n] * h[r];
            }
        }
#pragma unroll
        for (int m = 1; m < 64; m <<= 1) sA += __shfl_xor(sA, m, 64);
        const float s_ = 0.5f / sA;          // fold unpack /2 scale
        v2f sc; sc.x = s_; sc.y = s_;
#pragma unroll
        for (int r = 0; r < 16; ++r) v[r] = v[r] * sc;
    } else if (okA && okB && pow_one) {
        float sA = 0.0f, sB = 0.0f;
#pragma unroll
        for (int r = 0; r < 16; ++r) {
            const int n = r * 64 + l;
            const float baseA = (float)n - fracA;
            float hA = 0.5f - 0.5f * __cosf(TWO_PI * (baseA + off) * inv_wl);
            hA = (baseA >= hib || baseA <= lob) ? 0.0f : hA;
            sA += hA;
            v[r].x = xb[idxA + n] * hA;
            const float baseB = (float)n - fracB;
            float hB = 0.5f - 0.5f * __cosf(TWO_PI * (baseB + off) * inv_wl);
            hB = (baseB >= hib || baseB <= lob) ? 0.0f : hB;
            sB += hB;
            v[r].y = xb[idxB + n] * hB;
        }
#pragma unroll
        for (int m = 1; m < 64; m <<= 1) {
            sA += __shfl_xor(sA, m, 64);
            sB += __shfl_xor(sB, m, 64);
        }
        v2f sc; sc.x = 0.5f / sA; sc.y = 0.5f / sB;
#pragma unroll
        for (int r = 0; r < 16; ++r) v[r] = v[r] * sc;
    } else {
        // general path: two-pass inline taps (bounds + win_pow)
        float sA = 0.0f, sB = 0.0f;
#pragma unroll
        for (int r = 0; r < 16; ++r) {
            const int n = r * 64 + l;
            const float baseA = (float)n - fracA;
            float hA = 0.5f - 0.5f * __cosf(TWO_PI * (baseA + off) * inv_wl);
            hA = (baseA >= hib || baseA <= lob) ? 0.0f : hA;
            sA += hA;
            const float baseB = (float)n - fracB;
            float hB = 0.5f - 0.5f * __cosf(TWO_PI * (baseB + off) * inv_wl);
            hB = (baseB >= hib || baseB <= lob) ? 0.0f : hB;
            sB += hB;
        }
        for (int m = 1; m < 64; m <<= 1) {
            sA += __shfl_xor(sA, m, 64);
            sB += __shfl_xor(sB, m, 64);
        }
        const float iA = 1.0f / sA, iB = 1.0f / sB;
#pragma unroll
        for (int r = 0; r < 16; ++r) {
            const int n = r * 64 + l;
            float a = 0.0f, bb = 0.0f;
            if (hasA) {
                const float baseA = (float)n - fracA;
                float hA = 0.5f - 0.5f * __cosf(TWO_PI * (baseA + off) * inv_wl);
                hA = (baseA >= hib || baseA <= lob) ? 0.0f : hA;
                float tpv = hA * iA;
                if (!pow_one) tpv = powf(tpv, wp);
                const int ia = idxA + n;
                a = (ia >= 0 && ia < L_C) ? xb[ia] * (0.5f * tpv) : 0.0f;
            }
            if (hasB) {
                const float baseB = (float)n - fracB;
                float hB = 0.5f - 0.5f * __cosf(TWO_PI * (baseB + off) * inv_wl);
                hB = (baseB >= hib || baseB <= lob) ? 0.0f : hB;
                float tpv = hB * iB;
                if (!pow_one) tpv = powf(tpv, wp);
                const int ib = idxB + n;
                bb = (ib >= 0 && ib < L_C) ? xb[ib] * (0.5f * tpv) : 0.0f;
            }
            v[r].x = a;
            v[r].y = bb;
        }
    }

    // ---- 16-point DIF FFT over registers, packed (output i holds k1=BR4[i])
#pragma unroll
    for (int s = 0; s < 4; ++s) {
        const int half = (16 >> s) >> 1;
#pragma unroll
        for (int b0 = 0; b0 < 16; b0 += (16 >> s)) {
#pragma unroll
            for (int j = 0; j < 8; ++j) {
                if (j < half) {
                    const int i0 = b0 + j, i1 = b0 + j + half;
                    const v2f u = v[i0], ww = v[i1];
                    v[i0] = u + ww;                 // v_pk_add_f32
                    const v2f d = u - ww;           // v_pk_add_f32 (neg)
                    if ((j << s) == 0) {
                        v[i1] = d;
                    } else {
                        v2f cs;
                        cs.x = C16[j << s];
                        cs.y = S16[j << s];
                        v[i1] = cmul_pk(d, cs);
                    }
                }
            }
        }
    }

    // ---- twiddle W_1024^(l * k1): doubling tree, packed cmul apply.
    //      Also derives the lane-FFT base twiddle (c16,s16) = 16*theta1.
    float cu, su;
    {
        float c1, s1;
        __sincosf(-(TWO_PI / 1024.0f) * (float)l, &s1, &c1);
        const float c2 = c1 * c1 - s1 * s1,  s2 = 2.0f * c1 * s1;
        const float c4 = c2 * c2 - s2 * s2,  s4 = 2.0f * c2 * s2;
        const float c8 = c4 * c4 - s4 * s4,  s8 = 2.0f * c4 * s4;
        const float c3 = c1 * c2 - s1 * s2,  s3 = c1 * s2 + s1 * c2;
        const float c5 = c1 * c4 - s1 * s4,  s5 = c1 * s4 + s1 * c4;
        const float c6 = c2 * c4 - s2 * s4,  s6 = c2 * s4 + s2 * c4;
        const float c7 = c3 * c4 - s3 * s4,  s7 = c3 * s4 + s3 * c4;
        const float c9  = c1 * c8 - s1 * s8, s9  = c1 * s8 + s1 * c8;
        const float c10 = c2 * c8 - s2 * s8, s10 = c2 * s8 + s2 * c8;
        const float c11 = c3 * c8 - s3 * s8, s11 = c3 * s8 + s3 * c8;
        const float c12 = c4 * c8 - s4 * s8, s12 = c4 * s8 + s4 * c8;
        const float c13 = c5 * c8 - s5 * s8, s13 = c5 * s8 + s5 * c8;
        const float c14 = c6 * c8 - s6 * s8, s14 = c6 * s8 + s6 * c8;
        const float c15 = c7 * c8 - s7 * s8, s15 = c7 * s8 + s7 * c8;
        cu = c8 * c8 - s8 * s8;              // cos(16*theta1) = cos(-2pi l/64)
        su = 2.0f * c8 * s8;
#define TW(K) { v2f cs; cs.x = c##K; cs.y = s##K; \
                v[BR4[K]] = cmul_pk(v[BR4[K]], cs); }
        TW(1) TW(2) TW(3) TW(4) TW(5) TW(6) TW(7) TW(8)
        TW(9) TW(10) TW(11) TW(12) TW(13) TW(14) TW(15)
#undef TW
    }

    // ---- 64-point DIF FFT across lanes, fold-twiddle convention:
    //      d = v + sgn*p (high: v - p), angle -2*pi*l*2^s/64, 0 extra sincos.
    {
        // --- stage 0: xor32 via permlane32_swap both-halves ---
        {
            const bool hi_ = (l & 32) != 0;
            const float sgn = hi_ ? -1.0f : 1.0f;
            v2f tcs; tcs.x = hi_ ? cu : 1.0f; tcs.y = hi_ ? su : 0.0f;
#pragma unroll
            for (int i = 0; i < 16; ++i) {
                v2f d;
#if __has_builtin(__builtin_amdgcn_permlane32_swap)
                uv2 xr = __builtin_amdgcn_permlane32_swap(
                    __float_as_uint(v[i].x), __float_as_uint(v[i].x), false, false);
                uv2 xi = __builtin_amdgcn_permlane32_swap(
                    __float_as_uint(v[i].y), __float_as_uint(v[i].y), false, false);
                d.x = fmaf(sgn, __uint_as_float(xr.x), __uint_as_float(xr.y));
                d.y = fmaf(sgn, __uint_as_float(xi.x), __uint_as_float(xi.y));
#else
                d.x = fmaf(sgn, __shfl_xor(v[i].x, 32, 64), v[i].x);
                d.y = fmaf(sgn, __shfl_xor(v[i].y, 32, 64), v[i].y);
#endif
                v[i] = cmul_pk(d, tcs);
            }
            const float nc = fmaf(2.0f * cu, cu, -1.0f);
            su = 2.0f * cu * su; cu = nc;
        }
        // --- stage 1: xor16 via permlane16_swap both-halves ---
        {
            const bool hi_ = (l & 16) != 0;
            const float sgn = hi_ ? -1.0f : 1.0f;
            v2f tcs; tcs.x = hi_ ? cu : 1.0f; tcs.y = hi_ ? su : 0.0f;
#pragma unroll
            for (int i = 0; i < 16; ++i) {
                v2f d;
#if __has_builtin(__builtin_amdgcn_permlane16_swap)
                uv2 xr = __builtin_amdgcn_permlane16_swap(
                    __float_as_uint(v[i].x), __float_as_uint(v[i].x), false, false);
                uv2 xi = __builtin_amdgcn_permlane16_swap(
                    __float_as_uint(v[i].y), __float_as_uint(v[i].y), false, false);
                d.x = fmaf(sgn, __uint_as_float(xr.x), __uint_as_float(xr.y));
                d.y = fmaf(sgn, __uint_as_float(xi.x), __uint_as_float(xi.y));
#else
                d.x = fmaf(sgn, __shfl_xor(v[i].x, 16, 64), v[i].x);
                d.y = fmaf(sgn, __shfl_xor(v[i].y, 16, 64), v[i].y);
#endif
                v[i] = cmul_pk(d, tcs);
            }
            const float nc = fmaf(2.0f * cu, cu, -1.0f);
            su = 2.0f * cu * su; cu = nc;
        }
        // --- stages 2..4: xor8 (DPP), xor4 (swizzle), xor2 (DPP) ---
#define FOLD_STAGE(MASK, EXCH)                                                \
        {                                                                     \
            const bool hi_ = (l & (MASK)) != 0;                               \
            const float sgn = hi_ ? -1.0f : 1.0f;                             \
            v2f tcs; tcs.x = hi_ ? cu : 1.0f; tcs.y = hi_ ? su : 0.0f;        \
            _Pragma("unroll")                                                 \
            for (int i = 0; i < 16; ++i) {                                    \
                v2f d;                                                        \
                d.x = fmaf(sgn, EXCH(v[i].x), v[i].x);                        \
                d.y = fmaf(sgn, EXCH(v[i].y), v[i].y);                        \
                v[i] = cmul_pk(d, tcs);                                       \
            }                                                                 \
            const float nc = fmaf(2.0f * cu, cu, -1.0f);                      \
            su = 2.0f * cu * su; cu = nc;                                     \
        }
        FOLD_STAGE(8, lane_xor8)
        FOLD_STAGE(4, lane_xor4)
        FOLD_STAGE(2, lane_xor2)
#undef FOLD_STAGE
        // --- stage 5: xor1, twiddle == 1 -> plain butterfly ---
        {
            const float sgn = (l & 1) ? -1.0f : 1.0f;
#pragma unroll
            for (int i = 0; i < 16; ++i) {
                v[i].x = fmaf(sgn, v[i].x, lane_xor1(v[i].x));
                v[i].y = fmaf(sgn, v[i].y, lane_xor1(v[i].y));
            }
        }
    }
    // now (lane l, reg i) holds X[k'], k' = BR4[i] + 16*brev6(l)

    // ---- conjugate-symmetry unpack + magnitudes (all lanes productive)
    {
        // i = 0 (k1 == 0): self-mirrored k'=0 / k'=512 -> paired path
        {
            const float yr = __shfl(v[0].x, l2, 64);
            const float yi = __shfl(v[0].y, l2, 64);
            const int k = 16 * bl;
            if (k <= 512) {
                const float sa = v[0].x + yr, sb = v[0].y - yi;
                const float ua = v[0].y + yi, ub = yr - v[0].x;
                const int ka = k + (k >> 5);
                if (hasA) mag[2 * jp][ka] = fast_sqrtf(fmaf(sa, sa, sb * sb));
                if (hasB) mag[2 * jp + 1][ka] = fast_sqrtf(fmaf(ua, ua, ub * ub));
            }
        }
        // i >= 1: low lane (bl<32) -> |A[k']|; high -> |B[1024-k']|
        const bool lowk = (bl < 32);
        v2f sp; sp.x = lowk ? 1.0f : -1.0f; sp.y = lowk ? -1.0f : 1.0f;
        const int row = 2 * jp + (lowk ? 0 : 1);
        const bool wr_ok = lowk ? hasA : hasB;
#pragma unroll
        for (int i = 1; i < 16; ++i) {
            v2f y;
            y.x = lane_xor63(v[PARTNER[i]].x, l);
            y.y = lane_xor63(v[PARTNER[i]].y, l);
            const v2f t = y * sp + v[i];            // packed fma
            const float m = fast_sqrtf(fmaf(t.x, t.x, t.y * t.y));
            const int kp = BR4[i] + 16 * bl;
            const int k = lowk ? kp : (NN - kp);
            const int ka = k + (k >> 5);
            if (wr_ok) mag[row][ka] = m;
        }
    }

    __syncthreads();

    // ---- coalesced write-out: float2 along t (622 even -> 8B aligned)
    if (t0 + TT <= T_C) {
        for (int q = tid; q < F_C * 8; q += 512) {
            const int f = q >> 3;
            const int tg = (q & 7) << 1;
            const int fa = f + (f >> 5);
            float2 o;
            o.x = mag[tg + 0][fa];
            o.y = mag[tg + 1][fa];
            *(float2*)&out[((size_t)b * F_C + f) * T_C + t0 + tg] = o;
        }
    } else {
        for (int e = tid; e < F_C * TT; e += 512) {
            const int f = e >> 4;
            const int tt = e & 15;
            const int t = t0 + tt;
            if (t < T_C)
                out[((size_t)b * F_C + f) * T_C + t] = mag[tt][f + (f >> 5)];
        }
    }
}

extern "C" void kernel_launch(void* const* d_in, const int* in_sizes, int n_in,
                              void* d_out, int out_size, void* d_ws, size_t ws_size,
                              hipStream_t stream) {
    const float* x   = (const float*)d_in[0];
    const float* wl  = (const float*)d_in[1];
    const float* st  = (const float*)d_in[2];
    const float* wp  = (const float*)d_in[3];
    float* out = (float*)d_out;

    fftw_kernel<<<dim3(NBLK), dim3(512), 0, stream>>>(x, wl, st, wp, out);
}

// Round 23
// 60.525 us; speedup vs baseline: 1.0263x; 1.0263x over previous
//
#include <hip/hip_runtime.h>
#include <math.h>

#define NN 1024
#define B_C 64
#define L_C 160000
#define T_C 622
#define F_C 513
#define TT 16
#define NTILE ((T_C + TT - 1) / TT)   // 39
#define NBLK (B_C * NTILE)            // 2496 = 8 * 312
#define WIN_MIN_C (1024.0f / 20.0f)
#define WIN_MAX_C 1024.0f
#define TWO_PI 6.28318530717958647692f

typedef unsigned uv2 __attribute__((ext_vector_type(2)));
typedef float v2f __attribute__((ext_vector_type(2)));

__device__ __forceinline__ int brev6(int x) {
    return ((x & 1) << 5) | ((x & 2) << 3) | ((x & 4) << 1) |
           ((x & 8) >> 1) | ((x & 16) >> 3) | ((x & 32) >> 5);
}

// packed complex multiply: r = d * (cs.x + i*cs.y); d = {re, im}. 2 VOP3P ops.
__device__ __forceinline__ v2f cmul_pk(v2f d, v2f cs) {
    v2f t, r;
    asm("v_pk_mul_f32 %0, %1, %2 op_sel_hi:[1,0]"
        : "=v"(t) : "v"(d), "v"(cs));
    asm("v_pk_fma_f32 %0, %1, %2, %3 op_sel:[1,1,0] op_sel_hi:[0,1,1] neg_lo:[1,0,0]"
        : "=v"(r) : "v"(d), "v"(cs), "v"(t));
    return r;
}

// ---- lane-exchange helpers ----
__device__ __forceinline__ float lane_xor32(float v, int l) {
#if __has_builtin(__builtin_amdgcn_permlane32_swap)
    uv2 r = __builtin_amdgcn_permlane32_swap(__float_as_uint(v), __float_as_uint(v),
                                             false, false);
    return __uint_as_float((l & 32) ? r.x : r.y);
#else
    return __shfl_xor(v, 32, 64);
#endif
}
__device__ __forceinline__ float lane_xor8(float v) {   // row_ror:8 == xor8
    return __int_as_float(__builtin_amdgcn_update_dpp(
        __float_as_int(v), __float_as_int(v), 0x128, 0xF, 0xF, false));
}
__device__ __forceinline__ float lane_xor4(float v) {   // ds_swizzle xor4
    return __int_as_float(__builtin_amdgcn_ds_swizzle(__float_as_int(v), 0x101F));
}
__device__ __forceinline__ float lane_xor2(float v) {   // quad_perm [2,3,0,1]
    return __int_as_float(__builtin_amdgcn_update_dpp(
        __float_as_int(v), __float_as_int(v), 0x4E, 0xF, 0xF, false));
}
__device__ __forceinline__ float lane_xor1(float v) {   // quad_perm [1,0,3,2]
    return __int_as_float(__builtin_amdgcn_update_dpp(
        __float_as_int(v), __float_as_int(v), 0xB1, 0xF, 0xF, false));
}
__device__ __forceinline__ float lane_xor16(float v, int l) {
#if __has_builtin(__builtin_amdgcn_permlane16_swap)
    uv2 r = __builtin_amdgcn_permlane16_swap(__float_as_uint(v), __float_as_uint(v),
                                             false, false);
    return __uint_as_float((l & 16) ? r.x : r.y);
#else
    return __shfl_xor(v, 16, 64);
#endif
}
__device__ __forceinline__ float lane_xor31(float v) {  // ds_swizzle xor31
    return __int_as_float(__builtin_amdgcn_ds_swizzle(__float_as_int(v), 0x7C1F));
}
__device__ __forceinline__ float lane_xor63(float v, int l) {
    return lane_xor32(lane_xor31(v), l);   // 31 ^ 32 = 63, DS + VALU
}
__device__ __forceinline__ float fast_sqrtf(float x) {
#if __has_builtin(__builtin_amdgcn_sqrtf)
    return __builtin_amdgcn_sqrtf(x);
#else
    return sqrtf(x);
#endif
}

// --- Kernel: 8 waves/block, packed-fp32 FFT, inline taps, XCD-paired tiles ---
__global__ __launch_bounds__(512, 4) void fftw_kernel(
    const float* __restrict__ x,        // [B_C][L_C]
    const float* __restrict__ win_length,
    const float* __restrict__ strides,
    const float* __restrict__ win_pow,
    float* __restrict__ out)            // [B_C][F_C][T_C]
{
    // XCD-pairing remap: dispatch sends block i to XCD i%8. Map so that
    // work items 2p and 2p+1 (adjacent tiles, sharing write cachelines and
    // 75% of input) both land on the same XCD's L2.
    const int bid = blockIdx.x;                  // 0..NBLK-1
    const int xcd = bid & 7;
    const int slot = bid >> 3;                   // 0..311
    const int q_ = slot & 1;
    const int chunk = slot >> 1;                 // 0..155
    const int work = 2 * (xcd + 8 * chunk) + q_; // bijective on [0, NBLK)
    const int tile = work % NTILE;
    const int b = work / NTILE;

    const int t0 = tile * TT;
    const int tid = threadIdx.x;
    const int w = tid >> 6;      // wave id 0..7 = frame pair
    const int l = tid & 63;      // lane

    const float wl = fminf(fmaxf(win_length[0], WIN_MIN_C), WIN_MAX_C);
    const float st = fminf(fmaxf(strides[0], 0.0f), WIN_MAX_C);
    const float wp = win_pow[0];
    const bool pow_one = (wp == 1.0f);

    // Hann window parameters (wave-uniform)
    const float hib = ceilf(((float)NN - 1.0f + wl) * 0.5f);
    const float lob = floorf(((float)NN - 1.0f - wl) * 0.5f);
    const float off = (wl - (float)NN + 1.0f) * 0.5f;
    const float inv_wl = 1.0f / wl;

    const float* xb = x + (size_t)b * L_C;

    __shared__ float mag[TT][F_C + 16];   // 529-float rows: stride%32=17, coprime

    const int bl = brev6(l);
    const int l2 = brev6((64 - bl) & 63);   // unpack partner lane for k1==0 reg

    constexpr int BR4[16]     = {0,8,4,12,2,10,6,14,1,9,5,13,3,11,7,15};
    constexpr int PARTNER[16] = {0,1,3,2,7,6,5,4,15,14,13,12,11,10,9,8};
    constexpr float C16[8] = {1.0f, 0.92387953251f, 0.70710678119f, 0.38268343236f,
                              0.0f, -0.38268343236f, -0.70710678119f, -0.92387953251f};
    constexpr float S16[8] = {0.0f, -0.38268343236f, -0.70710678119f, -0.92387953251f,
                              -1.0f, -0.92387953251f, -0.70710678119f, -0.38268343236f};

    const int jp = w;                   // pair index 0..7
    const int tA = t0 + 2 * jp;
    const int tB = tA + 1;
    const bool hasA = (tA < T_C);
    const bool hasB = (tB < T_C);
    const float frameA = (float)tA * st;
    const float fracA = frameA - floorf(frameA);
    const float frameB = (float)tB * st;
    const float fracB = frameB - floorf(frameB);
    const int idxA = hasA ? (int)floorf(frameA) : 0;
    const int idxB = hasB ? (int)floorf(frameB) : 0;

    v2f v[16];   // v[i].x = frame A (re), v[i].y = frame B (im)

    // ---- load + inline-tap taper; wave-uniform in-bounds fast path
    const bool okA = hasA && (idxA >= 0) && (idxA + NN <= L_C);
    const bool okB = hasB && (idxB >= 0) && (idxB + NN <= L_C);
    if (okA && okB && pow_one) {
        if (fracA == fracB) {
            // shared window: one cos per element, one normalization
            float sA = 0.0f;
#pragma unroll
            for (int r = 0; r < 16; ++r) {
                const int n = r * 64 + l;
                const float baseA = (float)n - fracA;
                float hA = 0.5f - 0.5f * __cosf(TWO_PI * (baseA + off) * inv_wl);
                hA = (baseA >= hib || baseA <= lob) ? 0.0f : hA;
                sA += hA;
                v[r].x = xb[idxA + n] * hA;
                v[r].y = xb[idxB + n] * hA;
            }
#pragma unroll
            for (int m = 1; m < 64; m <<= 1) sA += __shfl_xor(sA, m, 64);
            const float s_ = 0.5f / sA;          // fold unpack /2 scale
            v2f sc; sc.x = s_; sc.y = s_;
#pragma unroll
            for (int r = 0; r < 16; ++r) v[r] = v[r] * sc;
        } else {
            float sA = 0.0f, sB = 0.0f;
#pragma unroll
            for (int r = 0; r < 16; ++r) {
                const int n = r * 64 + l;
                const float baseA = (float)n - fracA;
                float hA = 0.5f - 0.5f * __cosf(TWO_PI * (baseA + off) * inv_wl);
                hA = (baseA >= hib || baseA <= lob) ? 0.0f : hA;
                sA += hA;
                v[r].x = xb[idxA + n] * hA;
                const float baseB = (float)n - fracB;
                float hB = 0.5f - 0.5f * __cosf(TWO_PI * (baseB + off) * inv_wl);
                hB = (baseB >= hib || baseB <= lob) ? 0.0f : hB;
                sB += hB;
                v[r].y = xb[idxB + n] * hB;
            }
#pragma unroll
            for (int m = 1; m < 64; m <<= 1) {
                sA += __shfl_xor(sA, m, 64);
                sB += __shfl_xor(sB, m, 64);
            }
            v2f sc; sc.x = 0.5f / sA; sc.y = 0.5f / sB;
#pragma unroll
            for (int r = 0; r < 16; ++r) v[r] = v[r] * sc;
        }
    } else {
        // general path: two-pass inline taps (bounds + win_pow)
        float sA = 0.0f, sB = 0.0f;
#pragma unroll
        for (int r = 0; r < 16; ++r) {
            const int n = r * 64 + l;
            const float baseA = (float)n - fracA;
            float hA = 0.5f - 0.5f * __cosf(TWO_PI * (baseA + off) * inv_wl);
            hA = (baseA >= hib || baseA <= lob) ? 0.0f : hA;
            sA += hA;
            const float baseB = (float)n - fracB;
            float hB = 0.5f - 0.5f * __cosf(TWO_PI * (baseB + off) * inv_wl);
            hB = (baseB >= hib || baseB <= lob) ? 0.0f : hB;
            sB += hB;
        }
        for (int m = 1; m < 64; m <<= 1) {
            sA += __shfl_xor(sA, m, 64);
            sB += __shfl_xor(sB, m, 64);
        }
        const float iA = 1.0f / sA, iB = 1.0f / sB;
#pragma unroll
        for (int r = 0; r < 16; ++r) {
            const int n = r * 64 + l;
            float a = 0.0f, bb = 0.0f;
            if (hasA) {
                const float baseA = (float)n - fracA;
                float hA = 0.5f - 0.5f * __cosf(TWO_PI * (baseA + off) * inv_wl);
                hA = (baseA >= hib || baseA <= lob) ? 0.0f : hA;
                float tpv = hA * iA;
                if (!pow_one) tpv = powf(tpv, wp);
                const int ia = idxA + n;
                a = (ia >= 0 && ia < L_C) ? xb[ia] * (0.5f * tpv) : 0.0f;
            }
            if (hasB) {
                const float baseB = (float)n - fracB;
                float hB = 0.5f - 0.5f * __cosf(TWO_PI * (baseB + off) * inv_wl);
                hB = (baseB >= hib || baseB <= lob) ? 0.0f : hB;
                float tpv = hB * iB;
                if (!pow_one) tpv = powf(tpv, wp);
                const int ib = idxB + n;
                bb = (ib >= 0 && ib < L_C) ? xb[ib] * (0.5f * tpv) : 0.0f;
            }
            v[r].x = a;
            v[r].y = bb;
        }
    }

    // ---- 16-point DIF FFT over registers, packed (output i holds k1=BR4[i])
#pragma unroll
    for (int s = 0; s < 4; ++s) {
        const int half = (16 >> s) >> 1;
#pragma unroll
        for (int b0 = 0; b0 < 16; b0 += (16 >> s)) {
#pragma unroll
            for (int j = 0; j < 8; ++j) {
                if (j < half) {
                    const int i0 = b0 + j, i1 = b0 + j + half;
                    const v2f u = v[i0], ww = v[i1];
                    v[i0] = u + ww;                 // v_pk_add_f32
                    const v2f d = u - ww;           // v_pk_add_f32 (neg)
                    if ((j << s) == 0) {
                        v[i1] = d;
                    } else {
                        v2f cs;
                        cs.x = C16[j << s];
                        cs.y = S16[j << s];
                        v[i1] = cmul_pk(d, cs);
                    }
                }
            }
        }
    }

    // ---- twiddle W_1024^(l * k1): doubling tree, packed cmul apply
    {
        float c1, s1;
        __sincosf(-(TWO_PI / 1024.0f) * (float)l, &s1, &c1);
        const float c2 = c1 * c1 - s1 * s1,  s2 = 2.0f * c1 * s1;
        const float c4 = c2 * c2 - s2 * s2,  s4 = 2.0f * c2 * s2;
        const float c8 = c4 * c4 - s4 * s4,  s8 = 2.0f * c4 * s4;
        const float c3 = c1 * c2 - s1 * s2,  s3 = c1 * s2 + s1 * c2;
        const float c5 = c1 * c4 - s1 * s4,  s5 = c1 * s4 + s1 * c4;
        const float c6 = c2 * c4 - s2 * s4,  s6 = c2 * s4 + s2 * c4;
        const float c7 = c3 * c4 - s3 * s4,  s7 = c3 * s4 + s3 * c4;
        const float c9  = c1 * c8 - s1 * s8, s9  = c1 * s8 + s1 * c8;
        const float c10 = c2 * c8 - s2 * s8, s10 = c2 * s8 + s2 * c8;
        const float c11 = c3 * c8 - s3 * s8, s11 = c3 * s8 + s3 * c8;
        const float c12 = c4 * c8 - s4 * s8, s12 = c4 * s8 + s4 * c8;
        const float c13 = c5 * c8 - s5 * s8, s13 = c5 * s8 + s5 * c8;
        const float c14 = c6 * c8 - s6 * s8, s14 = c6 * s8 + s6 * c8;
        const float c15 = c7 * c8 - s7 * s8, s15 = c7 * s8 + s7 * c8;
#define TW(K) { v2f cs; cs.x = c##K; cs.y = s##K; \
                v[BR4[K]] = cmul_pk(v[BR4[K]], cs); }
        TW(1) TW(2) TW(3) TW(4) TW(5) TW(6) TW(7) TW(8)
        TW(9) TW(10) TW(11) TW(12) TW(13) TW(14) TW(15)
#undef TW
    }

    // ---- 64-point DIF FFT across lanes, fold-twiddle convention:
    //      d = v + sgn*p (high: v - p), angle -2*pi*l*2^s/64, 1 sincos total.
    {
        float cu, su;
        __sincosf(-(TWO_PI / 64.0f) * (float)l, &su, &cu);

        // --- stage 0: xor32 via permlane32_swap both-halves ---
        {
            const bool hi_ = (l & 32) != 0;
            const float sgn = hi_ ? -1.0f : 1.0f;
            v2f tcs; tcs.x = hi_ ? cu : 1.0f; tcs.y = hi_ ? su : 0.0f;
#pragma unroll
            for (int i = 0; i < 16; ++i) {
                v2f d;
#if __has_builtin(__builtin_amdgcn_permlane32_swap)
                uv2 xr = __builtin_amdgcn_permlane32_swap(
                    __float_as_uint(v[i].x), __float_as_uint(v[i].x), false, false);
                uv2 xi = __builtin_amdgcn_permlane32_swap(
                    __float_as_uint(v[i].y), __float_as_uint(v[i].y), false, false);
                d.x = fmaf(sgn, __uint_as_float(xr.x), __uint_as_float(xr.y));
                d.y = fmaf(sgn, __uint_as_float(xi.x), __uint_as_float(xi.y));
#else
                d.x = fmaf(sgn, __shfl_xor(v[i].x, 32, 64), v[i].x);
                d.y = fmaf(sgn, __shfl_xor(v[i].y, 32, 64), v[i].y);
#endif
                v[i] = cmul_pk(d, tcs);
            }
            const float nc = fmaf(2.0f * cu, cu, -1.0f);
            su = 2.0f * cu * su; cu = nc;
        }
        // --- stage 1: xor16 via permlane16_swap both-halves ---
        {
            const bool hi_ = (l & 16) != 0;
            const float sgn = hi_ ? -1.0f : 1.0f;
            v2f tcs; tcs.x = hi_ ? cu : 1.0f; tcs.y = hi_ ? su : 0.0f;
#pragma unroll
            for (int i = 0; i < 16; ++i) {
                v2f d;
#if __has_builtin(__builtin_amdgcn_permlane16_swap)
                uv2 xr = __builtin_amdgcn_permlane16_swap(
                    __float_as_uint(v[i].x), __float_as_uint(v[i].x), false, false);
                uv2 xi = __builtin_amdgcn_permlane16_swap(
                    __float_as_uint(v[i].y), __float_as_uint(v[i].y), false, false);
                d.x = fmaf(sgn, __uint_as_float(xr.x), __uint_as_float(xr.y));
                d.y = fmaf(sgn, __uint_as_float(xi.x), __uint_as_float(xi.y));
#else
                d.x = fmaf(sgn, __shfl_xor(v[i].x, 16, 64), v[i].x);
                d.y = fmaf(sgn, __shfl_xor(v[i].y, 16, 64), v[i].y);
#endif
                v[i] = cmul_pk(d, tcs);
            }
            const float nc = fmaf(2.0f * cu, cu, -1.0f);
            su = 2.0f * cu * su; cu = nc;
        }
        // --- stages 2..4: xor8 (DPP), xor4 (swizzle), xor2 (DPP) ---
#define FOLD_STAGE(MASK, EXCH)                                                \
        {                                                                     \
            const bool hi_ = (l & (MASK)) != 0;                               \
            const float sgn = hi_ ? -1.0f : 1.0f;                             \
            v2f tcs; tcs.x = hi_ ? cu : 1.0f; tcs.y = hi_ ? su : 0.0f;        \
            _Pragma("unroll")                                                 \
            for (int i = 0; i < 16; ++i) {                                    \
                v2f d;                                                        \
                d.x = fmaf(sgn, EXCH(v[i].x), v[i].x);                        \
                d.y = fmaf(sgn, EXCH(v[i].y), v[i].y);                        \
                v[i] = cmul_pk(d, tcs);                                       \
            }                                                                 \
            const float nc = fmaf(2.0f * cu, cu, -1.0f);                      \
            su = 2.0f * cu * su; cu = nc;                                     \
        }
        FOLD_STAGE(8, lane_xor8)
        FOLD_STAGE(4, lane_xor4)
        FOLD_STAGE(2, lane_xor2)
#undef FOLD_STAGE
        // --- stage 5: xor1, twiddle == 1 -> plain butterfly ---
        {
            const float sgn = (l & 1) ? -1.0f : 1.0f;
#pragma unroll
            for (int i = 0; i < 16; ++i) {
                v[i].x = fmaf(sgn, v[i].x, lane_xor1(v[i].x));
                v[i].y = fmaf(sgn, v[i].y, lane_xor1(v[i].y));
            }
        }
    }
    // now (lane l, reg i) holds X[k'], k' = BR4[i] + 16*brev6(l)

    // ---- conjugate-symmetry unpack + magnitudes (all lanes productive)
    {
        // i = 0 (k1 == 0): self-mirrored k'=0 / k'=512 -> paired path
        {
            const float yr = __shfl(v[0].x, l2, 64);
            const float yi = __shfl(v[0].y, l2, 64);
            const int k = 16 * bl;
            if (k <= 512) {
                const float sa = v[0].x + yr, sb = v[0].y - yi;
                const float ua = v[0].y + yi, ub = yr - v[0].x;
                const int ka = k + (k >> 5);
                if (hasA) mag[2 * jp][ka] = fast_sqrtf(fmaf(sa, sa, sb * sb));
                if (hasB) mag[2 * jp + 1][ka] = fast_sqrtf(fmaf(ua, ua, ub * ub));
            }
        }
        // i >= 1: low lane (bl<32) -> |A[k']|; high -> |B[1024-k']|
        const bool lowk = (bl < 32);
        v2f sp; sp.x = lowk ? 1.0f : -1.0f; sp.y = lowk ? -1.0f : 1.0f;
        const int row = 2 * jp + (lowk ? 0 : 1);
        const bool wr_ok = lowk ? hasA : hasB;
#pragma unroll
        for (int i = 1; i < 16; ++i) {
            v2f y;
            y.x = lane_xor63(v[PARTNER[i]].x, l);
            y.y = lane_xor63(v[PARTNER[i]].y, l);
            const v2f t = y * sp + v[i];            // packed fma
            const float m = fast_sqrtf(fmaf(t.x, t.x, t.y * t.y));
            const int kp = BR4[i] + 16 * bl;
            const int k = lowk ? kp : (NN - kp);
            const int ka = k + (k >> 5);
            if (wr_ok) mag[row][ka] = m;
        }
    }

    __syncthreads();

    // ---- coalesced write-out: float2 along t (622 even -> 8B aligned)
    if (t0 + TT <= T_C) {
        for (int q = tid; q < F_C * 8; q += 512) {
            const int f = q >> 3;
            const int tg = (q & 7) << 1;
            const int fa = f + (f >> 5);
            float2 o;
            o.x = mag[tg + 0][fa];
            o.y = mag[tg + 1][fa];
            *(float2*)&out[((size_t)b * F_C + f) * T_C + t0 + tg] = o;
        }
    } else {
        for (int e = tid; e < F_C * TT; e += 512) {
            const int f = e >> 4;
            const int tt = e & 15;
            const int t = t0 + tt;
            if (t < T_C)
                out[((size_t)b * F_C + f) * T_C + t] = mag[tt][f + (f >> 5)];
        }
    }
}

extern "C" void kernel_launch(void* const* d_in, const int* in_sizes, int n_in,
                              void* d_out, int out_size, void* d_ws, size_t ws_size,
                              hipStream_t stream) {
    const float* x   = (const float*)d_in[0];
    const float* wl  = (const float*)d_in[1];
    const float* st  = (const float*)d_in[2];
    const float* wp  = (const float*)d_in[3];
    float* out = (float*)d_out;

    fftw_kernel<<<dim3(NBLK), dim3(512), 0, stream>>>(x, wl, st, wp, out);
}